// Round 9
// baseline (189.238 us; speedup 1.0000x reference)
//
#include <hip/hip_runtime.h>
#include <cstdint>
#include <cstddef>

#define BB 16
#define NN 4096
#define CC 80
#define MAXD 100
#define IOU_T 0.5f
#define CONF_T 0.5f
#define RSTRIDE 81
#define PER_B (MAXD * 4 + MAXD * CC)   // 8400 output elems per batch
#define NWORDS (NN / 64)
#define BCAP 2048
#define SEGSZ 2048
#define HH 2048                        // head size (LDS-resident)
#define HW 32                          // head words (HH/64)

// fl32(inter/uni) > 0.5  <=>  inter > uni*(0.5+2^-25), evaluated EXACTLY in
// fp64 (24-bit x 25-bit mantissa product = 49 bits < 53). Bit-identical to
// the reference's IEEE divide + compare.
#define IOUC 0x1.000001p-1

// ---- workspace layout (fast path) ----
#define WS_KEYS   0x000000             // [B*N] u64 (og int list overlays)
#define WS_Y1S    0x080000             // [B*N] f32 each
#define WS_X1S    0x0C0000
#define WS_Y2S    0x100000
#define WS_X2S    0x140000
#define WS_ARS    0x180000
#define WS_NLIST  0x1C0000             // [B] int
#define WS_KIDX   0x1C0100             // [B*100] int
#define WS_CNT    0x1C2000             // [B] int
#define WS_NEED   0x200000             // 2 MB

// ---------------------------------------------------------------------------
// K1: softmax of (10x)^2 per row, one THREAD per row, 128 rows/block.
// numpy pairwise-8 sum DAG for s (bitwise == np); score = IEEE fl(1/s).
// ---------------------------------------------------------------------------
__global__ __launch_bounds__(128) void k_softmax(const float* __restrict__ cls_in,
                                                 float* __restrict__ probs,
                                                 uint64_t* __restrict__ keys) {
#pragma clang fp contract(off)
    __shared__ float buf[128 * RSTRIDE];
    int t = threadIdx.x;
    size_t gbase = (size_t)blockIdx.x * 128 * CC;

    for (int i = t; i < 128 * CC; i += 128) {
        int r = i / CC, c = i - r * CC;
        buf[r * RSTRIDE + c] = cls_in[gbase + i];
    }
    __syncthreads();

    float* row = buf + t * RSTRIDE;

    float m = -3.402823466e+38f;
    for (int c = 0; c < CC; ++c) {
        float y = row[c] * 10.0f;
        float z = y * y;
        m = fmaxf(m, z);
    }
    for (int c = 0; c < CC; ++c) {
        float y = row[c] * 10.0f;
        float z = y * y;
        row[c] = expf(z - m);
    }
    float r8[8];
    #pragma unroll
    for (int j = 0; j < 8; ++j) r8[j] = row[j];
    for (int i = 8; i < CC; i += 8) {
        #pragma unroll
        for (int j = 0; j < 8; ++j) r8[j] += row[i + j];
    }
    float s = ((r8[0] + r8[1]) + (r8[2] + r8[3])) + ((r8[4] + r8[5]) + (r8[6] + r8[7]));

    float score = 1.0f / s;
    for (int c = 0; c < CC; ++c) row[c] = row[c] * score;

    int gw = blockIdx.x * 128 + t;
    unsigned n = (unsigned)(gw & (NN - 1));
    keys[gw] = ((uint64_t)__float_as_uint(score) << 32)
             | (uint64_t)(0xFFFFFFFFu - n);

    __syncthreads();
    for (int i = t; i < 128 * CC; i += 128) {
        int r = i / CC, c = i - r * CC;
        probs[gbase + i] = buf[r * RSTRIDE + c];
    }
}

// ---------------------------------------------------------------------------
// K2: partition + dynamic-size B-sort + fused sorted-corner build.
// One block (1024 thr) per batch; blockIdx.x = b -> XCD b%8 (locality anchor).
// ---------------------------------------------------------------------------
__global__ __launch_bounds__(1024) void k_part(uint64_t* keys,
                                               const float* __restrict__ boxes,
                                               float* __restrict__ y1s, float* __restrict__ x1s,
                                               float* __restrict__ y2s, float* __restrict__ x2s,
                                               float* __restrict__ ars,
                                               int* __restrict__ nlist_g) {
#pragma clang fp contract(off)
    __shared__ uint64_t bbuf[BCAP];
    __shared__ int wsumA[16], wsumB[16];

    const int tid = threadIdx.x, lane = tid & 63, wv = tid >> 6;
    const int b = blockIdx.x;
    const uint64_t* kb = keys + (size_t)b * NN;
    int* og = (int*)(keys + (size_t)b * NN);
    size_t bN = (size_t)b * NN;

    uint64_t myk[4]; bool fa[4], fb[4];
    int asum = 0, bsum = 0;
    for (int k = 0; k < 4; ++k) {
        uint64_t key = kb[4 * tid + k]; myk[k] = key;
        unsigned hi = (unsigned)(key >> 32);
        fa[k] = (hi == 0x3F800000u);
        fb[k] = (__uint_as_float(hi) > CONF_T) && !fa[k];
        asum += fa[k] ? 1 : 0; bsum += fb[k] ? 1 : 0;
    }
    int ia = asum, ib = bsum;
    for (int off = 1; off < 64; off <<= 1) {
        int va = __shfl_up(ia, off), vb = __shfl_up(ib, off);
        if (lane >= off) { ia += va; ib += vb; }
    }
    if (lane == 63) { wsumA[wv] = ia; wsumB[wv] = ib; }
    __syncthreads();
    int baseA = 0, baseB = 0, cntA = 0, cntB = 0;
    for (int w2 = 0; w2 < 16; ++w2) {
        if (w2 < wv) { baseA += wsumA[w2]; baseB += wsumB[w2]; }
        cntA += wsumA[w2]; cntB += wsumB[w2];
    }
    int pA = baseA + (ia - asum);
    int pB = baseB + (ib - bsum);
    for (int k = 0; k < 4; ++k) {
        if (fa[k]) og[pA++] = 4 * tid + k;
        if (fb[k]) { if (pB < BCAP) bbuf[pB] = myk[k]; pB++; }
    }
    int cntBc = cntB < BCAP ? cntB : BCAP;
    int P2 = 64; while (P2 < cntBc) P2 <<= 1;
    for (int i = tid; i < P2; i += 1024) if (i >= cntBc) bbuf[i] = 0;
    __syncthreads();

    for (unsigned k2 = 2; k2 <= (unsigned)P2; k2 <<= 1) {
        for (unsigned j = k2 >> 1; j > 0; j >>= 1) {
            for (unsigned i = tid; i < (unsigned)P2; i += 1024) {
                unsigned p = i ^ j;
                if (p > i) {
                    uint64_t va = bbuf[i], vb = bbuf[p];
                    bool desc = ((i & k2) == 0);
                    if (desc ? (va < vb) : (va > vb)) { bbuf[i] = vb; bbuf[p] = va; }
                }
            }
            __syncthreads();
        }
    }
    for (int i = tid; i < cntBc; i += 1024)
        og[cntA + i] = (int)(0xFFFFFFFFu - (unsigned)(bbuf[i] & 0xFFFFFFFFull));
    int nl = cntA + cntBc;
    if (tid == 0) nlist_g[b] = nl;
    __syncthreads();

    const float* bxp = boxes + bN * 4;
    for (int i = tid; i < nl; i += 1024) {
        int o = og[i];
        float4 bv = ((const float4*)bxp)[o];
        float y1 = fminf(bv.x, bv.z), y2 = fmaxf(bv.x, bv.z);
        float x1 = fminf(bv.y, bv.w), x2 = fmaxf(bv.y, bv.w);
        y1s[bN + i] = y1; x1s[bN + i] = x1;
        y2s[bN + i] = y2; x2s[bN + i] = x2;
        ars[bN + i] = (y2 - y1) * (x2 - x1);
    }
}

// ---------------------------------------------------------------------------
// K3 (fused NMS): speculative batched sweep with ON-THE-FLY row compute.
// One block (1024 thr = 16 waves) per batch. Head corners LDS-resident.
// Loop: wave0 selects <=16 lowest live indices (rank-scan, register-only);
// all 16 waves compute their candidate's 2048-wide suppression row (fp64
// predicate, bit-exact); wave0 replays the exact greedy scan from LDS rows.
// No mask matrix, no 8 MB global traffic. Phases B/C handle the tail.
// ---------------------------------------------------------------------------
__global__ __launch_bounds__(1024) void k_nms2(const float* __restrict__ y1s, const float* __restrict__ x1s,
                                               const float* __restrict__ y2s, const float* __restrict__ x2s,
                                               const float* __restrict__ ars,
                                               const int* __restrict__ nlist_g,
                                               const uint64_t* __restrict__ keys,  // og overlay
                                               int* __restrict__ kidx_out,
                                               int* __restrict__ cnt_out) {
#pragma clang fp contract(off)
    __shared__ float hy1[HH], hx1[HH], hy2[HH], hx2[HH], har[HH];
    __shared__ uint64_t rowb[16][HW];
    __shared__ int cand_s[16];
    __shared__ float cmy1[16], cmy2[16], cmx1[16], cmx2[16], cmar[16];
    __shared__ int   cog[16];
    __shared__ float kky1[MAXD], kkx1[MAXD], kky2[MAXD], kkx2[MAXD], kkar[MAXD];
    __shared__ int   kkidx[MAXD];
    __shared__ uint64_t tailw[HW];
    __shared__ int state_s, kA_s, ktot_s;

    int b = blockIdx.x;
    int tid = threadIdx.x, lane = tid & 63, wv = tid >> 6;
    int nl = nlist_g[b];
    int Hc = nl < HH ? nl : HH;
    size_t bN = (size_t)b * NN;
    const int* og = (const int*)(keys + bN);

    // stage head corners (zero-fill pads -> inter=0, never suppress)
    for (int i = tid; i < HH; i += 1024) {
        bool v = i < Hc;
        hy1[i] = v ? y1s[bN + i] : 0.f;
        hx1[i] = v ? x1s[bN + i] : 0.f;
        hy2[i] = v ? y2s[bN + i] : 0.f;
        hx2[i] = v ? x2s[bN + i] : 0.f;
        har[i] = v ? ars[bN + i] : 0.f;
    }
    if (tid == 0) { state_s = 0; kA_s = 0; ktot_s = 0; }
    for (int i = tid; i < HW; i += 1024) tailw[i] = 0;

    // wave0 live bitmap (lane L covers indices 64L..64L+63)
    uint64_t live = 0;
    if (wv == 0) {
        int lo = 64 * lane;
        if (Hc <= lo) live = 0;
        else if (Hc >= lo + 64) live = ~0ull;
        else live = (1ull << (Hc - lo)) - 1ull;
    }
    int kept = 0;
    __syncthreads();   // corners staged (select below reads only registers/LDS scalars)

    // ---- initial select (wave0) ----
    if (wv == 0) {
        int pc = __popcll(live);
        int inc = pc;
        for (int off = 1; off < 64; off <<= 1) {
            int v = __shfl_up(inc, off);
            if (lane >= off) inc += v;
        }
        int ex = inc - pc;
        int total = __shfl(inc, 63);
        uint64_t t2 = live;
        while (t2 && ex < 16) {
            int bi = __ffsll((unsigned long long)t2) - 1;
            cand_s[ex] = 64 * lane + bi;
            ++ex; t2 &= t2 - 1;
        }
        int nc = total < 16 ? total : 16;
        if (lane == 0) {
            for (int s = nc; s < 16; ++s) cand_s[s] = -1;
            state_s = nc;
            if (nc == 0) { kA_s = 0; ktot_s = 0; }
        }
    }

    // ---- phase A loop ----
    for (;;) {
        __syncthreads();                 // B1: cand_s/state_s visible
        int st = state_s;
        if (st <= 0) break;

        // row compute: wave wv builds candidate cand_s[wv]'s row
        int ci = cand_s[wv];
        if (ci >= 0) {
            float a1 = hy1[ci], a3 = hx1[ci], a2 = hy2[ci], a4 = hx2[ci], aa = har[ci];
            for (int t3 = 0; t3 < HW; ++t3) {
                int j = t3 * 64 + lane;
                float ih = fmaxf(0.f, fminf(a2, hy2[j]) - fmaxf(a1, hy1[j]));
                float iw = fmaxf(0.f, fminf(a4, hx2[j]) - fmaxf(a3, hx1[j]));
                float inter = ih * iw;
                float uni = (aa + har[j]) - inter;
                bool s = (j > ci) && (inter > 0.f) &&
                         ((double)inter > (double)uni * IOUC);
                uint64_t w = __ballot(s);
                if (lane == 0) rowb[wv][t3] = w;
            }
            if (lane == 0) {
                cmy1[wv] = a1; cmy2[wv] = a2; cmx1[wv] = a3; cmx2[wv] = a4;
                cmar[wv] = aa; cog[wv] = og[ci];
            }
        }
        __syncthreads();                 // B2: rows + meta ready

        // replay + next select (wave0 only)
        if (wv == 0) {
            bool fin = false;
            for (int s = 0; s < st; ++s) {
                int cs = cand_s[s];
                int wi = cs >> 6, bi = cs & 63;
                uint64_t lw = __shfl(live, wi);
                if ((lw >> bi) & 1ull) {
                    uint64_t rw = (lane < HW) ? rowb[s][lane] : 0;
                    live &= ~rw;
                    if (lane == wi) live &= ~(1ull << bi);
                    if (lane == 0) {
                        kky1[kept] = cmy1[s]; kky2[kept] = cmy2[s];
                        kkx1[kept] = cmx1[s]; kkx2[kept] = cmx2[s];
                        kkar[kept] = cmar[s]; kkidx[kept] = cog[s];
                    }
                    ++kept;
                    if (kept >= MAXD) { fin = true; break; }
                }
            }
            if (st < 16) fin = true;     // live was exhausted by this batch
            if (fin) {
                if (lane == 0) { state_s = 0; kA_s = kept; ktot_s = kept; }
            } else {
                int pc = __popcll(live);
                int inc = pc;
                for (int off = 1; off < 64; off <<= 1) {
                    int v = __shfl_up(inc, off);
                    if (lane >= off) inc += v;
                }
                int ex = inc - pc;
                int total = __shfl(inc, 63);
                uint64_t t2 = live;
                while (t2 && ex < 16) {
                    int bi = __ffsll((unsigned long long)t2) - 1;
                    cand_s[ex] = 64 * lane + bi;
                    ++ex; t2 &= t2 - 1;
                }
                int nc = total < 16 ? total : 16;
                if (lane == 0) {
                    for (int s = nc; s < 16; ++s) cand_s[s] = -1;
                    state_s = nc;
                    if (nc == 0) { kA_s = kept; ktot_s = kept; }
                }
            }
        }
    }

    // ---- phase B: parallel tail suppression vs head keeps ----
    int kA = kA_s;
    if (nl > HH && kA < MAXD) {
        for (int rep = 0; rep < 2; ++rep) {
            int c = HH + rep * 1024 + tid;
            bool sup = (c >= nl);
            float y1 = y1s[bN + c], x1 = x1s[bN + c];
            float y2 = y2s[bN + c], x2 = x2s[bN + c];
            float ar = ars[bN + c];
            for (int q = 0; q < kA; ++q) {
                float ih = fmaxf(0.f, fminf(y2, kky2[q]) - fmaxf(y1, kky1[q]));
                float iw = fmaxf(0.f, fminf(x2, kkx2[q]) - fmaxf(x1, kkx1[q]));
                float inter = ih * iw;
                float uni = (ar + kkar[q]) - inter;
                sup = sup || (inter > 0.f && (double)inter > (double)uni * IOUC);
            }
            uint64_t balS = __ballot(!sup);
            if (lane == 0) tailw[rep * 16 + wv] = balS;
        }
    }
    __syncthreads();

    // ---- phase C: wave0 walks surviving tail candidates ----
    if (wv == 0 && nl > HH && kA < MAXD) {
        uint64_t tlive = (lane >= 32) ? tailw[lane - 32] : 0;
        int kc = kA;
        while (kc < MAXD) {
            uint64_t bal = __ballot(tlive != 0);
            if (!bal) break;
            int fl = __ffsll((unsigned long long)bal) - 1;
            uint64_t w0 = __shfl(tlive, fl);
            int bit = __ffsll((unsigned long long)w0) - 1;
            int c = HH + 64 * (fl - 32) + bit;
            if (lane == fl) tlive &= tlive - 1;

            float y1 = y1s[bN + c], x1 = x1s[bN + c];
            float y2 = y2s[bN + c], x2 = x2s[bN + c];
            float ar = ars[bN + c];
            bool hit = false;
            for (int q0 = kA; q0 < kc; q0 += 64) {
                int qi = q0 + lane;
                bool p = false;
                if (qi < kc) {
                    float ih = fmaxf(0.f, fminf(y2, kky2[qi]) - fmaxf(y1, kky1[qi]));
                    float iw = fmaxf(0.f, fminf(x2, kkx2[qi]) - fmaxf(x1, kkx1[qi]));
                    float inter = ih * iw;
                    float uni = (ar + kkar[qi]) - inter;
                    p = (inter > 0.f) && ((double)inter > (double)uni * IOUC);
                }
                if (__ballot(p)) { hit = true; break; }
            }
            if (!hit) {
                if (lane == 0) {
                    kky1[kc] = y1; kkx1[kc] = x1;
                    kky2[kc] = y2; kkx2[kc] = x2;
                    kkar[kc] = ar; kkidx[kc] = og[c];
                }
                ++kc;
            }
        }
        if (lane == 0) ktot_s = kc;
    }
    __syncthreads();

    int kt = ktot_s;
    if (tid == 0) cnt_out[b] = kt;
    for (int i = tid; i < MAXD; i += 1024)
        kidx_out[b * MAXD + i] = (i < kt) ? kkidx[i] : 0;
}

// ---------------------------------------------------------------------------
// K4: wide parallel gather (unchanged).
// ---------------------------------------------------------------------------
__global__ __launch_bounds__(256) void k_gather(const float* __restrict__ boxes,
                                                const float* __restrict__ probs,
                                                const int* __restrict__ kidx,
                                                const int* __restrict__ cnt,
                                                float* __restrict__ out_box,
                                                float* __restrict__ out_cls) {
    int u = blockIdx.x * 256 + threadIdx.x;
    if (u >= BB * PER_B) return;
    int b = u / PER_B;
    int r = u - b * PER_B;
    int count = cnt[b];
    float val = 0.0f;
    if (r < MAXD * 4) {
        int t = r >> 2, e = r & 3;
        if (t < count) {
            int idx = kidx[b * MAXD + t];
            val = boxes[((size_t)b * NN + idx) * 4 + e];
        }
        out_box[(size_t)b * MAXD * 4 + r] = val;
    } else {
        int q = r - MAXD * 4;
        int t = q / CC, c = q - t * CC;
        if (t < count) {
            int idx = kidx[b * MAXD + t];
            val = probs[((size_t)b * NN + idx) * CC + c];
        }
        out_cls[(size_t)b * MAXD * CC + q] = val;
    }
}

// ---------------------------------------------------------------------------
// FALLBACK (ws too small): round-4 fused k_nms — verified passing.
// ---------------------------------------------------------------------------
__global__ __launch_bounds__(1024) void k_nms_fb(uint64_t* keys,
                                                 const float* __restrict__ boxes,
                                                 int* __restrict__ kidx_out,
                                                 int* __restrict__ cnt_out) {
#pragma clang fp contract(off)
    __shared__ float sy1[SEGSZ], sx1[SEGSZ], sy2[SEGSZ], sx2[SEGSZ];
    __shared__ int   soidx[SEGSZ];
    __shared__ uint64_t bbuf[BCAP];
    __shared__ uint64_t sup[NWORDS];
    __shared__ float ky1[MAXD], kx1[MAXD], ky2[MAXD], kx2[MAXD], kar[MAXD];
    __shared__ int   keptidx[MAXD];
    __shared__ int   wsumA[16], wsumB[16];
    __shared__ int   keptcnt_s, ctrl_s, seg_s;

    const int tid = threadIdx.x, lane = tid & 63, wv = tid >> 6;
    const int b = blockIdx.x;
    const uint64_t* kb = keys + (size_t)b * NN;
    const float* bxp = boxes + (size_t)b * NN * 4;
    int* og = (int*)(keys + (size_t)b * NN);

    uint64_t myk[4]; bool fa[4], fb[4];
    int asum = 0, bsum = 0;
    for (int k = 0; k < 4; ++k) {
        uint64_t key = kb[4 * tid + k]; myk[k] = key;
        unsigned hi = (unsigned)(key >> 32);
        fa[k] = (hi == 0x3F800000u);
        fb[k] = (__uint_as_float(hi) > CONF_T) && !fa[k];
        asum += fa[k] ? 1 : 0; bsum += fb[k] ? 1 : 0;
    }
    int ia = asum, ib = bsum;
    for (int off = 1; off < 64; off <<= 1) {
        int va = __shfl_up(ia, off), vb = __shfl_up(ib, off);
        if (lane >= off) { ia += va; ib += vb; }
    }
    if (lane == 63) { wsumA[wv] = ia; wsumB[wv] = ib; }
    __syncthreads();
    int baseA = 0, baseB = 0, cntA = 0, cntB = 0;
    for (int w2 = 0; w2 < 16; ++w2) {
        if (w2 < wv) { baseA += wsumA[w2]; baseB += wsumB[w2]; }
        cntA += wsumA[w2]; cntB += wsumB[w2];
    }
    int pA = baseA + (ia - asum);
    int pB = baseB + (ib - bsum);
    for (int k = 0; k < 4; ++k) {
        if (fa[k]) og[pA++] = 4 * tid + k;
        if (fb[k]) { if (pB < BCAP) bbuf[pB] = myk[k]; pB++; }
    }
    int cntBc = cntB < BCAP ? cntB : BCAP;
    int nlist = cntA + cntBc;
    if (tid == 0) { keptcnt_s = 0; seg_s = 0; }
    for (int i = tid; i < BCAP; i += 1024) if (i >= cntB) bbuf[i] = 0;
    __syncthreads();

    for (unsigned k2 = 2; k2 <= BCAP; k2 <<= 1) {
        for (unsigned j = k2 >> 1; j > 0; j >>= 1) {
            for (unsigned i = tid; i < BCAP; i += 1024) {
                unsigned p = i ^ j;
                if (p > i) {
                    uint64_t va = bbuf[i], vb = bbuf[p];
                    bool desc = ((i & k2) == 0);
                    if (desc ? (va < vb) : (va > vb)) { bbuf[i] = vb; bbuf[p] = va; }
                }
            }
            __syncthreads();
        }
    }
    for (int i = tid; i < cntBc; i += 1024)
        og[cntA + i] = (int)(0xFFFFFFFFu - (unsigned)(bbuf[i] & 0xFFFFFFFFull));
    if (tid < NWORDS) {
        int lo = tid * 64;
        uint64_t mm;
        if (nlist <= lo) mm = ~0ull;
        else if (nlist >= lo + 64) mm = 0ull;
        else mm = (~0ull) << (nlist - lo);
        sup[tid] = mm;
    }
    __syncthreads();

    for (int i = tid; i < SEGSZ; i += 1024) {
        if (i < nlist) {
            int o = og[i];
            soidx[i] = o;
            const float* bp = bxp + (size_t)o * 4;
            float b0 = bp[0], b1 = bp[1], b2 = bp[2], b3 = bp[3];
            sy1[i] = fminf(b0, b2); sy2[i] = fmaxf(b0, b2);
            sx1[i] = fminf(b1, b3); sx2[i] = fmaxf(b1, b3);
        }
    }
    __syncthreads();

    int curw = 0, segr = 0;
    while (true) {
        if (tid == 0) {
            int code = -1;
            for (;;) {
                int wend = (segr + 1) * (SEGSZ / 64);
                if (curw >= wend) {
                    if (segr == 0 && nlist > SEGSZ) {
                        code = -2; segr = 1; seg_s = 1; curw = SEGSZ / 64;
                    } else code = -1;
                    break;
                }
                uint64_t live = ~sup[curw];
                if (live) {
                    int j = __ffsll((unsigned long long)live) - 1;
                    int sel = curw * 64 + j;
                    int li = sel - segr * SEGSZ;
                    int kc = keptcnt_s;
                    keptidx[kc] = soidx[li];
                    ky1[kc] = sy1[li]; kx1[kc] = sx1[li];
                    ky2[kc] = sy2[li]; kx2[kc] = sx2[li];
                    kar[kc] = (sy2[li] - sy1[li]) * (sx2[li] - sx1[li]);
                    keptcnt_s = kc + 1;
                    sup[curw] |= (1ull << j);
                    code = (kc + 1 >= MAXD) ? -1 : sel;
                    break;
                }
                ++curw;
            }
            ctrl_s = code;
        }
        __syncthreads();
        int c = ctrl_s;
        if (c == -1) break;

        if (c == -2) {
            for (int i = tid; i < SEGSZ; i += 1024) {
                int gi = SEGSZ + i;
                if (gi < nlist) {
                    int o = og[gi];
                    soidx[i] = o;
                    const float* bp = bxp + (size_t)o * 4;
                    float b0 = bp[0], b1 = bp[1], b2 = bp[2], b3 = bp[3];
                    sy1[i] = fminf(b0, b2); sy2[i] = fmaxf(b0, b2);
                    sx1[i] = fminf(b1, b3); sx2[i] = fmaxf(b1, b3);
                }
            }
            __syncthreads();
            int kc = keptcnt_s;
            for (int k = 0; k < 2; ++k) {
                int li = tid + k * 1024;
                float y1 = sy1[li], y2 = sy2[li], x1 = sx1[li], x2 = sx2[li];
                float ar = (y2 - y1) * (x2 - x1);
                bool s = false;
                for (int q = 0; q < kc; ++q) {
                    float ih = fmaxf(0.f, fminf(y2, ky2[q]) - fmaxf(y1, ky1[q]));
                    float iw = fmaxf(0.f, fminf(x2, kx2[q]) - fmaxf(x1, kx1[q]));
                    float inter = ih * iw;
                    float uni = (ar + kar[q]) - inter;
                    s = s || (inter > 0.f && inter / uni > IOU_T);
                }
                uint64_t bal = __ballot(s);
                if (lane == 0 && bal) {
                    int word = (SEGSZ + k * 1024 + wv * 64) >> 6;
                    sup[word] |= bal;
                }
            }
            __syncthreads();
            continue;
        }

        int sg = seg_s;
        int cl = c - sg * SEGSZ;
        float cy1 = sy1[cl], cy2 = sy2[cl], cx1 = sx1[cl], cx2 = sx2[cl];
        float car = (cy2 - cy1) * (cx2 - cx1);
        for (int k = 0; k < 2; ++k) {
            int li = tid + k * 1024;
            float y1 = sy1[li], y2 = sy2[li], x1 = sx1[li], x2 = sx2[li];
            float ar = (y2 - y1) * (x2 - x1);
            float ih = fmaxf(0.f, fminf(y2, cy2) - fmaxf(y1, cy1));
            float iw = fmaxf(0.f, fminf(x2, cx2) - fmaxf(x1, cx1));
            float inter = ih * iw;
            float uni = (ar + car) - inter;
            bool s = (inter > 0.f) && (inter / uni > IOU_T);
            uint64_t bal = __ballot(s);
            if (lane == 0 && bal) {
                int word = (sg * SEGSZ + k * 1024 + wv * 64) >> 6;
                sup[word] |= bal;
            }
        }
        __syncthreads();
    }

    if (tid == 0) cnt_out[b] = keptcnt_s;
    for (int i = tid; i < MAXD; i += 1024)
        kidx_out[b * MAXD + i] = (i < keptcnt_s) ? keptidx[i] : 0;
}

extern "C" void kernel_launch(void* const* d_in, const int* in_sizes, int n_in,
                              void* d_out, int out_size, void* d_ws, size_t ws_size,
                              hipStream_t stream) {
    const float* boxes = (const float*)d_in[0];   // [B,N,4]
    const float* cls   = (const float*)d_in[1];   // [B,N,C]
    float* out = (float*)d_out;
    float* out_box = out;                                                  // [B,100,4]
    float* out_cls = out + (size_t)BB * MAXD * 4;                          // [B,100,80]
    float* probs   = out + (size_t)BB * MAXD * 4 + (size_t)BB * MAXD * CC; // [B,N,80]

    char* ws = (char*)d_ws;
    uint64_t* keys = (uint64_t*)(ws + WS_KEYS);

    k_softmax<<<(BB * NN) / 128, 128, 0, stream>>>(cls, probs, keys);

    if (ws_size >= (size_t)WS_NEED) {
        float* y1s = (float*)(ws + WS_Y1S);
        float* x1s = (float*)(ws + WS_X1S);
        float* y2s = (float*)(ws + WS_Y2S);
        float* x2s = (float*)(ws + WS_X2S);
        float* ars = (float*)(ws + WS_ARS);
        int* nlist = (int*)(ws + WS_NLIST);
        int* kidx  = (int*)(ws + WS_KIDX);
        int* cnt   = (int*)(ws + WS_CNT);

        k_part<<<BB, 1024, 0, stream>>>(keys, boxes, y1s, x1s, y2s, x2s, ars, nlist);
        k_nms2<<<BB, 1024, 0, stream>>>(y1s, x1s, y2s, x2s, ars, nlist,
                                        keys, kidx, cnt);
        k_gather<<<(BB * PER_B + 255) / 256, 256, 0, stream>>>(boxes, probs, kidx, cnt,
                                                               out_box, out_cls);
    } else {
        int* kidx = (int*)(ws + (size_t)BB * NN * sizeof(uint64_t));
        int* cnt  = kidx + BB * MAXD;
        k_nms_fb<<<BB, 1024, 0, stream>>>(keys, boxes, kidx, cnt);
        k_gather<<<(BB * PER_B + 255) / 256, 256, 0, stream>>>(boxes, probs, kidx, cnt,
                                                               out_box, out_cls);
    }
}

// Round 10
// 177.047 us; speedup vs baseline: 1.0689x; 1.0689x over previous
//
#include <hip/hip_runtime.h>
#include <cstdint>
#include <cstddef>

#define BB 16
#define NN 4096
#define CC 80
#define MAXD 100
#define CONF_T 0.5f
#define RSTRIDE 81
#define PER_B (MAXD * 4 + MAXD * CC)   // 8400 output elems per batch
#define NWORDS 64                      // 4096/64 bitmap words
#define BCAP 4096                      // B-group capacity (no truncation)
#define FBCAP 2048                     // fallback kernel's capacity
#define SEGSZ 2048

// fl32(inter/uni) > 0.5  <=>  inter > uni*(0.5+2^-25), evaluated EXACTLY in
// fp64 (24-bit x 25-bit mantissa product = 49 bits < 53). Bit-identical to
// the reference's IEEE divide + compare. (verified passing rounds 9)
#define IOUC 0x1.000001p-1

// ---- workspace layout (fast path) ----
#define WS_KEYS   0x000000             // [B*N] u64 (og int list overlays)
#define WS_Y1S    0x080000             // [B*N] f32 each
#define WS_X1S    0x0C0000
#define WS_Y2S    0x100000
#define WS_X2S    0x140000
#define WS_ARS    0x180000
#define WS_NLIST  0x1C0000             // [B] int
#define WS_KIDX   0x1C0100             // [B*100] int
#define WS_CNT    0x1C2000             // [B] int
#define WS_NEED   0x200000             // 2 MB

// ---------------------------------------------------------------------------
// K1: softmax of (10x)^2 per row, one THREAD per row, 128 rows/block.
// numpy pairwise-8 sum DAG for s (bitwise == np); score = IEEE fl(1/s).
// ---------------------------------------------------------------------------
__global__ __launch_bounds__(128) void k_softmax(const float* __restrict__ cls_in,
                                                 float* __restrict__ probs,
                                                 uint64_t* __restrict__ keys) {
#pragma clang fp contract(off)
    __shared__ float buf[128 * RSTRIDE];
    int t = threadIdx.x;
    size_t gbase = (size_t)blockIdx.x * 128 * CC;

    for (int i = t; i < 128 * CC; i += 128) {
        int r = i / CC, c = i - r * CC;
        buf[r * RSTRIDE + c] = cls_in[gbase + i];
    }
    __syncthreads();

    float* row = buf + t * RSTRIDE;

    float m = -3.402823466e+38f;
    for (int c = 0; c < CC; ++c) {
        float y = row[c] * 10.0f;
        float z = y * y;
        m = fmaxf(m, z);
    }
    for (int c = 0; c < CC; ++c) {
        float y = row[c] * 10.0f;
        float z = y * y;
        row[c] = expf(z - m);
    }
    float r8[8];
    #pragma unroll
    for (int j = 0; j < 8; ++j) r8[j] = row[j];
    for (int i = 8; i < CC; i += 8) {
        #pragma unroll
        for (int j = 0; j < 8; ++j) r8[j] += row[i + j];
    }
    float s = ((r8[0] + r8[1]) + (r8[2] + r8[3])) + ((r8[4] + r8[5]) + (r8[6] + r8[7]));

    float score = 1.0f / s;
    for (int c = 0; c < CC; ++c) row[c] = row[c] * score;

    int gw = blockIdx.x * 128 + t;
    unsigned n = (unsigned)(gw & (NN - 1));
    keys[gw] = ((uint64_t)__float_as_uint(score) << 32)
             | (uint64_t)(0xFFFFFFFFu - n);

    __syncthreads();
    for (int i = t; i < 128 * CC; i += 128) {
        int r = i / CC, c = i - r * CC;
        probs[gbase + i] = buf[r * RSTRIDE + c];
    }
}

// ---------------------------------------------------------------------------
// K2: partition + RANK-sort of B + fused sorted-corner build.
// Rank sort replaces the ~55-barrier bitonic: rank_i = #{j: key_j > key_i}
// (keys unique), cntB^2 broadcast compares, ONE barrier.
// ---------------------------------------------------------------------------
__global__ __launch_bounds__(1024) void k_part(uint64_t* keys,
                                               const float* __restrict__ boxes,
                                               float* __restrict__ y1s, float* __restrict__ x1s,
                                               float* __restrict__ y2s, float* __restrict__ x2s,
                                               float* __restrict__ ars,
                                               int* __restrict__ nlist_g) {
#pragma clang fp contract(off)
    __shared__ uint64_t bbuf[BCAP];
    __shared__ int wsumA[16], wsumB[16];

    const int tid = threadIdx.x, lane = tid & 63, wv = tid >> 6;
    const int b = blockIdx.x;
    const uint64_t* kb = keys + (size_t)b * NN;
    int* og = (int*)(keys + (size_t)b * NN);
    size_t bN = (size_t)b * NN;

    uint64_t myk[4]; bool fa[4], fb[4];
    int asum = 0, bsum = 0;
    for (int k = 0; k < 4; ++k) {
        uint64_t key = kb[4 * tid + k]; myk[k] = key;   // all reads precede og scatter
        unsigned hi = (unsigned)(key >> 32);
        fa[k] = (hi == 0x3F800000u);
        fb[k] = (__uint_as_float(hi) > CONF_T) && !fa[k];
        asum += fa[k] ? 1 : 0; bsum += fb[k] ? 1 : 0;
    }
    int ia = asum, ib = bsum;                       // wave-inclusive scans
    for (int off = 1; off < 64; off <<= 1) {
        int va = __shfl_up(ia, off), vb = __shfl_up(ib, off);
        if (lane >= off) { ia += va; ib += vb; }
    }
    if (lane == 63) { wsumA[wv] = ia; wsumB[wv] = ib; }
    __syncthreads();
    int baseA = 0, baseB = 0, cntA = 0, cntB = 0;
    for (int w2 = 0; w2 < 16; ++w2) {
        if (w2 < wv) { baseA += wsumA[w2]; baseB += wsumB[w2]; }
        cntA += wsumA[w2]; cntB += wsumB[w2];
    }
    int pA = baseA + (ia - asum);
    int pB = baseB + (ib - bsum);
    for (int k = 0; k < 4; ++k) {
        if (fa[k]) og[pA++] = 4 * tid + k;          // stable: idx order
        if (fb[k]) bbuf[pB++] = myk[k];             // pB < cntB <= 4096 always
    }
    __syncthreads();

    // rank sort of B (descending): one barrier total
    for (int i = tid; i < cntB; i += 1024) {
        uint64_t ki = bbuf[i];
        int rank = 0;
        for (int j = 0; j < cntB; ++j) rank += (bbuf[j] > ki) ? 1 : 0;
        og[cntA + rank] = (int)(0xFFFFFFFFu - (unsigned)(ki & 0xFFFFFFFFull));
    }
    int nl = cntA + cntB;
    if (tid == 0) nlist_g[b] = nl;
    __syncthreads();   // og complete & visible block-wide

    // fused sorted corner/area build
    const float* bxp = boxes + bN * 4;
    for (int i = tid; i < nl; i += 1024) {
        int o = og[i];
        float4 bv = ((const float4*)bxp)[o];
        float y1 = fminf(bv.x, bv.z), y2 = fmaxf(bv.x, bv.z);
        float x1 = fminf(bv.y, bv.w), x2 = fmaxf(bv.y, bv.w);
        y1s[bN + i] = y1; x1s[bN + i] = x1;
        y2s[bN + i] = y2; x2s[bN + i] = x2;
        ars[bN + i] = (y2 - y1) * (x2 - x1);
    }
}

// ---------------------------------------------------------------------------
// K3: filter-first bitmap NMS. One block (1024 thr = 16 waves) per batch.
// All nl (<=4096) sorted corners LDS-resident; unified 64-word live bitmap.
// Batch loop: select 64 lowest live -> 64x64 intra-batch kill matrix ->
// exact greedy 64-slot replay -> parallel filter of remaining live bits
// against the new keeps. No suppression rows, no mask matrix. ~2-3 batches.
// Order-exactness: every keep has lower sorted index than any still-live
// candidate (selection takes lowest), so filter+replay == reference greedy.
// ---------------------------------------------------------------------------
__global__ __launch_bounds__(1024) void k_nms3(const float* __restrict__ y1s, const float* __restrict__ x1s,
                                               const float* __restrict__ y2s, const float* __restrict__ x2s,
                                               const float* __restrict__ ars,
                                               const int* __restrict__ nlist_g,
                                               const uint64_t* __restrict__ keys,  // og overlay
                                               int* __restrict__ kidx_out,
                                               int* __restrict__ cnt_out) {
#pragma clang fp contract(off)
    __shared__ float hy1[NN], hx1[NN], hy2[NN], hx2[NN], har[NN];  // 80 KB
    __shared__ uint64_t live_lds[NWORDS];
    __shared__ uint64_t kill[64];
    __shared__ int cand_s[64];
    __shared__ int kpos[MAXD];
    __shared__ int state_s, kept_s, fk0_s, done_s;

    int b = blockIdx.x;
    int tid = threadIdx.x, lane = tid & 63, wv = tid >> 6;
    int nl = nlist_g[b]; if (nl > NN) nl = NN;
    size_t bN = (size_t)b * NN;

    for (int i = tid; i < NN; i += 1024) {
        bool v = i < nl;
        hy1[i] = v ? y1s[bN + i] : 0.f;
        hx1[i] = v ? x1s[bN + i] : 0.f;
        hy2[i] = v ? y2s[bN + i] : 0.f;
        hx2[i] = v ? x2s[bN + i] : 0.f;
        har[i] = v ? ars[bN + i] : 0.f;
    }
    if (tid < NWORDS) {
        int lo = tid * 64;
        uint64_t m;
        if (nl <= lo) m = 0ull;
        else if (nl >= lo + 64) m = ~0ull;
        else m = (1ull << (nl - lo)) - 1ull;
        live_lds[tid] = m;
    }
    if (tid == 0) { state_s = 0; kept_s = 0; fk0_s = 0; done_s = 0; }

    for (;;) {
        __syncthreads();                               // B1
        // ---- select up to 64 lowest live (wave0, register scan) ----
        if (wv == 0) {
            uint64_t lw = live_lds[lane];
            int pc = __popcll(lw);
            int inc = pc;
            for (int off = 1; off < 64; off <<= 1) {
                int v = __shfl_up(inc, off);
                if (lane >= off) inc += v;
            }
            int ex0 = inc - pc;
            int total = __shfl(inc, 63);
            int nc = total < 64 ? total : 64;
            uint64_t t2 = lw; int ex = ex0;
            while (t2 && ex < 64) {
                int bi = __ffsll((unsigned long long)t2) - 1;
                cand_s[ex] = 64 * lane + bi;
                ++ex; t2 &= t2 - 1;
            }
            int ntake = nc - ex0;
            if (ntake < 0) ntake = 0;
            if (ntake > pc) ntake = pc;
            uint64_t lw2 = lw;
            for (int k = 0; k < ntake; ++k) lw2 &= lw2 - 1;   // clear selected
            live_lds[lane] = lw2;
            if (lane == 0) {
                for (int s = nc; s < 64; ++s) cand_s[s] = -1;
                state_s = nc;
            }
        }
        __syncthreads();                               // B2
        int st = state_s;
        if (st <= 0) break;

        // ---- 64x64 intra-batch kill matrix: wave w rows t = w+16r ----
        {
            int cj = cand_s[lane];
            bool jv = cj >= 0;
            int cjx = jv ? cj : 0;
            float jy1 = hy1[cjx], jx1 = hx1[cjx], jy2 = hy2[cjx], jx2 = hx2[cjx], jar = har[cjx];
            #pragma unroll
            for (int r = 0; r < 4; ++r) {
                int t = wv + 16 * r;
                int ct = cand_s[t];
                bool tv = ct >= 0;
                int ctx = tv ? ct : 0;
                float ty1 = hy1[ctx], tx1 = hx1[ctx], ty2 = hy2[ctx], tx2 = hx2[ctx], tar = har[ctx];
                float ih = fmaxf(0.f, fminf(ty2, jy2) - fmaxf(ty1, jy1));
                float iw = fmaxf(0.f, fminf(tx2, jx2) - fmaxf(tx1, jx1));
                float inter = ih * iw;
                float uni = (tar + jar) - inter;
                bool s = tv && jv && (inter > 0.f) && ((double)inter > (double)uni * IOUC);
                uint64_t w = __ballot(s);
                if (lane == 0) kill[t] = w;
            }
        }
        __syncthreads();                               // B3
        // ---- exact greedy 64-slot replay (wave0) ----
        if (wv == 0) {
            uint64_t suppressed = 0, keptmask = 0;
            for (int j2 = 0; j2 < st; ++j2) {
                if (!((suppressed >> j2) & 1ull)) {
                    keptmask |= 1ull << j2;
                    suppressed |= kill[j2];
                }
            }
            int k0 = kept_s;
            if ((keptmask >> lane) & 1ull) {
                int pos = k0 + __popcll(keptmask & ((1ull << lane) - 1ull));
                if (pos < MAXD) kpos[pos] = cand_s[lane];
            }
            int k1 = k0 + __popcll(keptmask);
            if (lane == 0) {
                fk0_s = k0;
                kept_s = k1;
                done_s = (k1 >= MAXD || st < 64) ? 1 : 0;
            }
        }
        __syncthreads();                               // B4
        if (done_s) break;

        // ---- parallel filter of live bits vs new keeps (all 16 waves) ----
        {
            int f0 = fk0_s;
            int f1 = kept_s; if (f1 > MAXD) f1 = MAXD;
            #pragma unroll
            for (int r = 0; r < 4; ++r) {
                int g = wv + 16 * r;                   // word index, wave-uniform
                uint64_t lw = live_lds[g];
                if (!lw) continue;
                int idx = 64 * g + lane;
                bool alive = (lw >> lane) & 1ull;
                float y1 = hy1[idx], x1 = hx1[idx], y2 = hy2[idx], x2 = hx2[idx], ar = har[idx];
                bool sup = false;
                for (int q0 = f0; q0 < f1; q0 += 64) {
                    // preload up to 64 keep corners into lanes, broadcast via shfl
                    int qi = q0 + lane;
                    int kp = (qi < f1) ? kpos[qi] : 0;
                    float ky1 = hy1[kp], kx1 = hx1[kp], ky2 = hy2[kp], kx2 = hx2[kp], kar = har[kp];
                    int qn = f1 - q0; if (qn > 64) qn = 64;
                    for (int q = 0; q < qn; ++q) {
                        float qy1 = __shfl(ky1, q), qx1 = __shfl(kx1, q);
                        float qy2 = __shfl(ky2, q), qx2 = __shfl(kx2, q);
                        float qar = __shfl(kar, q);
                        float ih = fmaxf(0.f, fminf(y2, qy2) - fmaxf(y1, qy1));
                        float iw = fmaxf(0.f, fminf(x2, qx2) - fmaxf(x1, qx1));
                        float inter = ih * iw;
                        float uni = (ar + qar) - inter;
                        sup = sup || (inter > 0.f && (double)inter > (double)uni * IOUC);
                    }
                }
                uint64_t bal = __ballot(alive && sup);
                if (lane == 0 && bal) live_lds[g] = lw & ~bal;
            }
        }
    }

    int kt = kept_s; if (kt > MAXD) kt = MAXD;
    const int* og = (const int*)(keys + bN);
    if (tid == 0) cnt_out[b] = kt;
    if (tid < MAXD) kidx_out[b * MAXD + tid] = (tid < kt) ? og[kpos[tid]] : 0;
}

// ---------------------------------------------------------------------------
// K4: wide parallel gather (unchanged).
// ---------------------------------------------------------------------------
__global__ __launch_bounds__(256) void k_gather(const float* __restrict__ boxes,
                                                const float* __restrict__ probs,
                                                const int* __restrict__ kidx,
                                                const int* __restrict__ cnt,
                                                float* __restrict__ out_box,
                                                float* __restrict__ out_cls) {
    int u = blockIdx.x * 256 + threadIdx.x;
    if (u >= BB * PER_B) return;
    int b = u / PER_B;
    int r = u - b * PER_B;
    int count = cnt[b];
    float val = 0.0f;
    if (r < MAXD * 4) {
        int t = r >> 2, e = r & 3;
        if (t < count) {
            int idx = kidx[b * MAXD + t];
            val = boxes[((size_t)b * NN + idx) * 4 + e];
        }
        out_box[(size_t)b * MAXD * 4 + r] = val;
    } else {
        int q = r - MAXD * 4;
        int t = q / CC, c = q - t * CC;
        if (t < count) {
            int idx = kidx[b * MAXD + t];
            val = probs[((size_t)b * NN + idx) * CC + c];
        }
        out_cls[(size_t)b * MAXD * CC + q] = val;
    }
}

// ---------------------------------------------------------------------------
// FALLBACK (ws too small): round-4 fused k_nms — verified passing.
// ---------------------------------------------------------------------------
__global__ __launch_bounds__(1024) void k_nms_fb(uint64_t* keys,
                                                 const float* __restrict__ boxes,
                                                 int* __restrict__ kidx_out,
                                                 int* __restrict__ cnt_out) {
#pragma clang fp contract(off)
    __shared__ float sy1[SEGSZ], sx1[SEGSZ], sy2[SEGSZ], sx2[SEGSZ];
    __shared__ int   soidx[SEGSZ];
    __shared__ uint64_t bbuf[FBCAP];
    __shared__ uint64_t sup[NWORDS];
    __shared__ float ky1[MAXD], kx1[MAXD], ky2[MAXD], kx2[MAXD], kar[MAXD];
    __shared__ int   keptidx[MAXD];
    __shared__ int   wsumA[16], wsumB[16];
    __shared__ int   keptcnt_s, ctrl_s, seg_s;

    const int tid = threadIdx.x, lane = tid & 63, wv = tid >> 6;
    const int b = blockIdx.x;
    const uint64_t* kb = keys + (size_t)b * NN;
    const float* bxp = boxes + (size_t)b * NN * 4;
    int* og = (int*)(keys + (size_t)b * NN);

    uint64_t myk[4]; bool fa[4], fb[4];
    int asum = 0, bsum = 0;
    for (int k = 0; k < 4; ++k) {
        uint64_t key = kb[4 * tid + k]; myk[k] = key;
        unsigned hi = (unsigned)(key >> 32);
        fa[k] = (hi == 0x3F800000u);
        fb[k] = (__uint_as_float(hi) > CONF_T) && !fa[k];
        asum += fa[k] ? 1 : 0; bsum += fb[k] ? 1 : 0;
    }
    int ia = asum, ib = bsum;
    for (int off = 1; off < 64; off <<= 1) {
        int va = __shfl_up(ia, off), vb = __shfl_up(ib, off);
        if (lane >= off) { ia += va; ib += vb; }
    }
    if (lane == 63) { wsumA[wv] = ia; wsumB[wv] = ib; }
    __syncthreads();
    int baseA = 0, baseB = 0, cntA = 0, cntB = 0;
    for (int w2 = 0; w2 < 16; ++w2) {
        if (w2 < wv) { baseA += wsumA[w2]; baseB += wsumB[w2]; }
        cntA += wsumA[w2]; cntB += wsumB[w2];
    }
    int pA = baseA + (ia - asum);
    int pB = baseB + (ib - bsum);
    for (int k = 0; k < 4; ++k) {
        if (fa[k]) og[pA++] = 4 * tid + k;
        if (fb[k]) { if (pB < FBCAP) bbuf[pB] = myk[k]; pB++; }
    }
    int cntBc = cntB < FBCAP ? cntB : FBCAP;
    int nlist = cntA + cntBc;
    if (tid == 0) { keptcnt_s = 0; seg_s = 0; }
    for (int i = tid; i < FBCAP; i += 1024) if (i >= cntB) bbuf[i] = 0;
    __syncthreads();

    for (unsigned k2 = 2; k2 <= FBCAP; k2 <<= 1) {
        for (unsigned j = k2 >> 1; j > 0; j >>= 1) {
            for (unsigned i = tid; i < FBCAP; i += 1024) {
                unsigned p = i ^ j;
                if (p > i) {
                    uint64_t va = bbuf[i], vb = bbuf[p];
                    bool desc = ((i & k2) == 0);
                    if (desc ? (va < vb) : (va > vb)) { bbuf[i] = vb; bbuf[p] = va; }
                }
            }
            __syncthreads();
        }
    }
    for (int i = tid; i < cntBc; i += 1024)
        og[cntA + i] = (int)(0xFFFFFFFFu - (unsigned)(bbuf[i] & 0xFFFFFFFFull));
    if (tid < NWORDS) {
        int lo = tid * 64;
        uint64_t mm;
        if (nlist <= lo) mm = ~0ull;
        else if (nlist >= lo + 64) mm = 0ull;
        else mm = (~0ull) << (nlist - lo);
        sup[tid] = mm;
    }
    __syncthreads();

    for (int i = tid; i < SEGSZ; i += 1024) {
        if (i < nlist) {
            int o = og[i];
            soidx[i] = o;
            const float* bp = bxp + (size_t)o * 4;
            float b0 = bp[0], b1 = bp[1], b2 = bp[2], b3 = bp[3];
            sy1[i] = fminf(b0, b2); sy2[i] = fmaxf(b0, b2);
            sx1[i] = fminf(b1, b3); sx2[i] = fmaxf(b1, b3);
        }
    }
    __syncthreads();

    int curw = 0, segr = 0;
    while (true) {
        if (tid == 0) {
            int code = -1;
            for (;;) {
                int wend = (segr + 1) * (SEGSZ / 64);
                if (curw >= wend) {
                    if (segr == 0 && nlist > SEGSZ) {
                        code = -2; segr = 1; seg_s = 1; curw = SEGSZ / 64;
                    } else code = -1;
                    break;
                }
                uint64_t live = ~sup[curw];
                if (live) {
                    int j = __ffsll((unsigned long long)live) - 1;
                    int sel = curw * 64 + j;
                    int li = sel - segr * SEGSZ;
                    int kc = keptcnt_s;
                    keptidx[kc] = soidx[li];
                    ky1[kc] = sy1[li]; kx1[kc] = sx1[li];
                    ky2[kc] = sy2[li]; kx2[kc] = sx2[li];
                    kar[kc] = (sy2[li] - sy1[li]) * (sx2[li] - sx1[li]);
                    keptcnt_s = kc + 1;
                    sup[curw] |= (1ull << j);
                    code = (kc + 1 >= MAXD) ? -1 : sel;
                    break;
                }
                ++curw;
            }
            ctrl_s = code;
        }
        __syncthreads();
        int c = ctrl_s;
        if (c == -1) break;

        if (c == -2) {
            for (int i = tid; i < SEGSZ; i += 1024) {
                int gi = SEGSZ + i;
                if (gi < nlist) {
                    int o = og[gi];
                    soidx[i] = o;
                    const float* bp = bxp + (size_t)o * 4;
                    float b0 = bp[0], b1 = bp[1], b2 = bp[2], b3 = bp[3];
                    sy1[i] = fminf(b0, b2); sy2[i] = fmaxf(b0, b2);
                    sx1[i] = fminf(b1, b3); sx2[i] = fmaxf(b1, b3);
                }
            }
            __syncthreads();
            int kc = keptcnt_s;
            for (int k = 0; k < 2; ++k) {
                int li = tid + k * 1024;
                float y1 = sy1[li], y2 = sy2[li], x1 = sx1[li], x2 = sx2[li];
                float ar = (y2 - y1) * (x2 - x1);
                bool s = false;
                for (int q = 0; q < kc; ++q) {
                    float ih = fmaxf(0.f, fminf(y2, ky2[q]) - fmaxf(y1, ky1[q]));
                    float iw = fmaxf(0.f, fminf(x2, kx2[q]) - fmaxf(x1, kx1[q]));
                    float inter = ih * iw;
                    float uni = (ar + kar[q]) - inter;
                    s = s || (inter > 0.f && inter / uni > 0.5f);
                }
                uint64_t bal = __ballot(s);
                if (lane == 0 && bal) {
                    int word = (SEGSZ + k * 1024 + wv * 64) >> 6;
                    sup[word] |= bal;
                }
            }
            __syncthreads();
            continue;
        }

        int sg = seg_s;
        int cl = c - sg * SEGSZ;
        float cy1 = sy1[cl], cy2 = sy2[cl], cx1 = sx1[cl], cx2 = sx2[cl];
        float car = (cy2 - cy1) * (cx2 - cx1);
        for (int k = 0; k < 2; ++k) {
            int li = tid + k * 1024;
            float y1 = sy1[li], y2 = sy2[li], x1 = sx1[li], x2 = sx2[li];
            float ar = (y2 - y1) * (x2 - x1);
            float ih = fmaxf(0.f, fminf(y2, cy2) - fmaxf(y1, cy1));
            float iw = fmaxf(0.f, fminf(x2, cx2) - fmaxf(x1, cx1));
            float inter = ih * iw;
            float uni = (ar + car) - inter;
            bool s = (inter > 0.f) && (inter / uni > 0.5f);
            uint64_t bal = __ballot(s);
            if (lane == 0 && bal) {
                int word = (sg * SEGSZ + k * 1024 + wv * 64) >> 6;
                sup[word] |= bal;
            }
        }
        __syncthreads();
    }

    if (tid == 0) cnt_out[b] = keptcnt_s;
    for (int i = tid; i < MAXD; i += 1024)
        kidx_out[b * MAXD + i] = (i < keptcnt_s) ? keptidx[i] : 0;
}

extern "C" void kernel_launch(void* const* d_in, const int* in_sizes, int n_in,
                              void* d_out, int out_size, void* d_ws, size_t ws_size,
                              hipStream_t stream) {
    const float* boxes = (const float*)d_in[0];   // [B,N,4]
    const float* cls   = (const float*)d_in[1];   // [B,N,C]
    float* out = (float*)d_out;
    float* out_box = out;                                                  // [B,100,4]
    float* out_cls = out + (size_t)BB * MAXD * 4;                          // [B,100,80]
    float* probs   = out + (size_t)BB * MAXD * 4 + (size_t)BB * MAXD * CC; // [B,N,80]

    char* ws = (char*)d_ws;
    uint64_t* keys = (uint64_t*)(ws + WS_KEYS);

    k_softmax<<<(BB * NN) / 128, 128, 0, stream>>>(cls, probs, keys);

    if (ws_size >= (size_t)WS_NEED) {
        float* y1s = (float*)(ws + WS_Y1S);
        float* x1s = (float*)(ws + WS_X1S);
        float* y2s = (float*)(ws + WS_Y2S);
        float* x2s = (float*)(ws + WS_X2S);
        float* ars = (float*)(ws + WS_ARS);
        int* nlist = (int*)(ws + WS_NLIST);
        int* kidx  = (int*)(ws + WS_KIDX);
        int* cnt   = (int*)(ws + WS_CNT);

        k_part<<<BB, 1024, 0, stream>>>(keys, boxes, y1s, x1s, y2s, x2s, ars, nlist);
        k_nms3<<<BB, 1024, 0, stream>>>(y1s, x1s, y2s, x2s, ars, nlist,
                                        keys, kidx, cnt);
        k_gather<<<(BB * PER_B + 255) / 256, 256, 0, stream>>>(boxes, probs, kidx, cnt,
                                                               out_box, out_cls);
    } else {
        int* kidx = (int*)(ws + (size_t)BB * NN * sizeof(uint64_t));
        int* cnt  = kidx + BB * MAXD;
        k_nms_fb<<<BB, 1024, 0, stream>>>(keys, boxes, kidx, cnt);
        k_gather<<<(BB * PER_B + 255) / 256, 256, 0, stream>>>(boxes, probs, kidx, cnt,
                                                               out_box, out_cls);
    }
}